// Round 9
// baseline (885.496 us; speedup 1.0000x reference)
//
#include <hip/hip_runtime.h>
#include <hip/hip_bf16.h>

#define B_ 8
#define C_ 256
#define H_ 128
#define W_ 128
#define HW_ 16384
#define CHW_ (C_ * HW_)
#define NH_ 8
#define HD_ 32
#define NTOT (B_ * CHW_)   // 33,554,432

typedef short short8 __attribute__((ext_vector_type(8)));
typedef float f32x4 __attribute__((ext_vector_type(4)));

// ---------------- weight fp32 -> bf16 convert ----------------
__global__ __launch_bounds__(256) void wconv_kernel(const float* __restrict__ vw,
                                                    const float* __restrict__ ow,
                                                    __hip_bfloat16* __restrict__ wvb,
                                                    __hip_bfloat16* __restrict__ wob) {
    int i = blockIdx.x * 256 + threadIdx.x;   // 65536
    wvb[i] = __float2bfloat16(vw[i]);
    wob[i] = __float2bfloat16(ow[i]);
}

// ---------------- x [b][c][p] fp32 -> xT [b][p][c] bf16 (LDS-tiled transpose) ----------------
__global__ __launch_bounds__(256) void xt_kernel(const float* __restrict__ x,
                                                 __hip_bfloat16* __restrict__ xT) {
    __shared__ float tile[64][68];
    int t = threadIdx.x;
    int p0 = blockIdx.x * 64, c0 = blockIdx.y * 64, b = blockIdx.z;
    const float* xb = x + ((size_t)b * C_ + c0) * HW_ + p0;
#pragma unroll
    for (int l = 0; l < 4; ++l) {
        int idx = t + 256 * l;
        int row = idx >> 4, cf = idx & 15;
        float4 v = *(const float4*)&xb[(size_t)row * HW_ + cf * 4];
        *(float4*)&tile[row][cf * 4] = v;
    }
    __syncthreads();
    __hip_bfloat16* op = xT + ((size_t)b * HW_ + p0) * C_ + c0;
#pragma unroll
    for (int l = 0; l < 2; ++l) {
        int idx = t + 256 * l;
        int p = idx & 63, oct = idx >> 6;    // oct 0..7
        __hip_bfloat16 arr[8];
#pragma unroll
        for (int j = 0; j < 8; ++j) arr[j] = __float2bfloat16(tile[oct * 8 + j][p]);
        *(int4*)(op + (size_t)p * C_ + oct * 8) = *(int4*)arr;
    }
}

// ---------------- FUSED dwconv3x3 + partial offset projection ----------------
__global__ __launch_bounds__(256) void fused_offset_kernel(const float* __restrict__ x,
                                                           const float* __restrict__ dww,
                                                           const float* __restrict__ offw,
                                                           float* __restrict__ partials) {
    __shared__ float xt[4][10][136];   // 4 ch, 10 halo rows, col+4 shift, pad
    __shared__ float wT[32][16];
    __shared__ float wd[32][9];
    int t = threadIdx.x;
    int rt = blockIdx.x, cg = blockIdx.y, b = blockIdx.z;
    int h0 = rt * 8, c0 = cg * 32;
    for (int i = t; i < 512; i += 256) { int o = i >> 5, c = i & 31; wT[c][o] = offw[o * 256 + c0 + c]; }
    for (int i = t; i < 288; i += 256) { wd[i / 9][i % 9] = dww[(c0 + i / 9) * 9 + i % 9]; }
    const float* xb = x + ((size_t)b * C_ + c0) * HW_;
    int col = t & 127;
    int sb = (t >> 7) * 4;             // row-strip base 0 or 4
    float acc[4][16] = {};
    for (int cc0 = 0; cc0 < 32; cc0 += 4) {
        __syncthreads();
#pragma unroll
        for (int l = 0; l < 5; ++l) {
            int idx = t + 256 * l;             // 0..1279
            int pr = idx >> 5, c4 = idx & 31;
            int cc = pr / 10, r = pr - cc * 10;
            int gh = h0 - 1 + r;
            float4 v = make_float4(0.f, 0.f, 0.f, 0.f);
            if (gh >= 0 && gh < H_)
                v = *(const float4*)&xb[(size_t)(cc0 + cc) * HW_ + gh * W_ + c4 * 4];
            *(float4*)&xt[cc][r][4 + c4 * 4] = v;
        }
        if (t < 80) { int pr = t >> 1, side = t & 1; xt[pr / 10][pr % 10][side ? 132 : 3] = 0.f; }
        __syncthreads();
#pragma unroll
        for (int cc = 0; cc < 4; ++cc) {
            float win[6][3];
#pragma unroll
            for (int rr = 0; rr < 6; ++rr)
#pragma unroll
                for (int kk = 0; kk < 3; ++kk)
                    win[rr][kk] = xt[cc][sb + rr][col + 3 + kk];
            float w9[9];
#pragma unroll
            for (int k9 = 0; k9 < 9; ++k9) w9[k9] = wd[cc0 + cc][k9];
#pragma unroll
            for (int j = 0; j < 4; ++j) {
                float s = 0.f;
#pragma unroll
                for (int ky = 0; ky < 3; ++ky)
#pragma unroll
                    for (int kx = 0; kx < 3; ++kx)
                        s += win[j + ky][kx] * w9[ky * 3 + kx];
#pragma unroll
                for (int o = 0; o < 16; ++o) acc[j][o] += s * wT[cc0 + cc][o];
            }
        }
    }
    float* pb = partials + (size_t)(cg * 8 + b) * 16 * HW_;
#pragma unroll
    for (int o = 0; o < 16; ++o)
#pragma unroll
        for (int j = 0; j < 4; ++j)
            pb[(size_t)o * HW_ + (h0 + sb + j) * W_ + col] = acc[j][o];
}

// ---------------- sum 8 partials + bias + fast tanh ----------------
__global__ __launch_bounds__(256) void offreduce_kernel(const float* __restrict__ partials,
                                                        const float* __restrict__ offb,
                                                        float* __restrict__ off_buf) {
    int i = blockIdx.x * 256 + threadIdx.x;     // 0..2097151 over [b][o][p]
    float s = 0.f;
#pragma unroll
    for (int cg = 0; cg < 8; ++cg) s += partials[(size_t)cg * 2097152 + i];
    int o = (i >> 14) & 15;
    float z = s + offb[o];
    // tanh(z) = 1 - 2/(exp2(2z*log2e)+1)  (exact; v_exp_f32-based, saturates at +/-1)
    float e = exp2f(z * 2.885390082f);
    off_buf[i] = (1.0f - __fdividef(2.0f, e + 1.0f)) * 0.5f;
}

// ---------------- bf16 MFMA GEMM: Y[b](256 x HW) = W(256x256) * X[b], X given as X^T [p][c] ----------------
// Concurrency-widened R8 skeleton: ONE m-tile = full M=256 (8 waves x 32 m-rows), N-tile 128,
// 512 threads, BK=32, 8 steps. LDS 48KB (A dbuf 2x16KB + B dbuf 2x8KB) -> 3 blocks/CU = 24 waves.
// X read ONCE (no duplicate m-half blocks). Same per-wave ILP as R8 (16 MFMA / 10 ds_read / step).
//  - global_load_lds width=16 DMA staging; next step staged BEFORE compute; one barrier/step.
//  - LDS linear for DMA; global SOURCE slot XOR-swizzled; ds_read same XOR (both-sides involution).
//  - TRANS epilogue: two 64-row halves staged via LDS (stride 264), coalesced 512B row writes.
// TRANS: write Y^T [n][c] as bf16 (for sampling).  STATS: accumulate group sum/sumsq.
template<bool TRANS, bool STATS>
__global__ __launch_bounds__(512, 6) void mfma_gemm(const __hip_bfloat16* __restrict__ Wb,
                                                    const __hip_bfloat16* __restrict__ Xt,
                                                    void* __restrict__ Y,
                                                    float* __restrict__ stats) {
    // 24576 shorts = 48KB: A dbuf [2][8192] at 0, B dbuf [2][4096] at 16384.
    // TRANS epilogue reuse: [64 rows][264 stride] = 16896 shorts.
    __shared__ __align__(16) short smem[24576];
    int t = threadIdx.x;
    int wave = t >> 6, lane = t & 63;
    int quad = lane >> 4, l16 = lane & 15;
    int b = blockIdx.z;
    int n0 = blockIdx.x * 128;
    const short* Wp = (const short*)Wb;                                   // full 256 x 256
    const short* Xp = (const short*)Xt + ((size_t)b * HW_ + n0) * 256;

    // staging: A tile = 1024 chunks of 16B (256 rows x 4 slots), 2/thread; B tile = 512 chunks, 1/thread.
    // LDS dest lane-linear (DMA semantics); global src slot XOR-swizzled.
    int iA0 = t, iA1 = t + 512;
    int rA0 = iA0 >> 2, rA1 = iA1 >> 2;
    int sA0 = (iA0 & 3) ^ ((rA0 >> 1) & 3);
    int sA1 = (iA1 & 3) ^ ((rA1 >> 1) & 3);
    int rB0 = t >> 2;
    int sB0 = (t & 3) ^ ((rB0 >> 1) & 3);

#define STAGE(buf, ko)                                                                                          \
    do {                                                                                                        \
        short* Asm_ = smem + (buf) * 8192;                                                                      \
        short* Bsm_ = smem + 16384 + (buf) * 4096;                                                              \
        __builtin_amdgcn_global_load_lds(Wp + (size_t)rA0 * 256 + (ko) + sA0 * 8, Asm_ + iA0 * 8, 16, 0, 0);    \
        __builtin_amdgcn_global_load_lds(Wp + (size_t)rA1 * 256 + (ko) + sA1 * 8, Asm_ + iA1 * 8, 16, 0, 0);    \
        __builtin_amdgcn_global_load_lds(Xp + (size_t)rB0 * 256 + (ko) + sB0 * 8, Bsm_ + t * 8, 16, 0, 0);      \
    } while (0)

    f32x4 acc[2][8];
#pragma unroll
    for (int mt = 0; mt < 2; ++mt)
#pragma unroll
        for (int nt = 0; nt < 8; ++nt) acc[mt][nt] = (f32x4){0.f, 0.f, 0.f, 0.f};

    STAGE(0, 0);
    __syncthreads();                       // drain prologue stage

#pragma unroll
    for (int kk = 0; kk < 8; ++kk) {
        int cur = kk & 1;
        if (kk < 7) STAGE(cur ^ 1, (kk + 1) * 32);   // prefetch next tile BEFORE compute
        __builtin_amdgcn_sched_barrier(0);            // pin DMA issue above the ds_reads
        const short* Ac = smem + cur * 8192;
        const short* Bc = smem + 16384 + cur * 4096;
        short8 af[2], bf[8];
#pragma unroll
        for (int mt = 0; mt < 2; ++mt) {
            int r = wave * 32 + mt * 16 + l16;        // 0..255
            int sl = quad ^ ((r >> 1) & 3);
            af[mt] = *(const short8*)&Ac[r * 32 + sl * 8];
        }
#pragma unroll
        for (int nt = 0; nt < 8; ++nt) {
            int r = nt * 16 + l16;                    // 0..127
            int sl = quad ^ ((r >> 1) & 3);
            bf[nt] = *(const short8*)&Bc[r * 32 + sl * 8];
        }
#pragma unroll
        for (int mt = 0; mt < 2; ++mt)
#pragma unroll
            for (int nt = 0; nt < 8; ++nt)
                acc[mt][nt] = __builtin_amdgcn_mfma_f32_16x16x32_bf16(af[mt], bf[nt], acc[mt][nt], 0, 0, 0);
        __syncthreads();                   // ONE barrier/step: drains prefetch (issued pre-compute)
    }
#undef STAGE

    if constexpr (TRANS) {
        // two 64-n-row halves: stage [64][264] bf16 in LDS, then coalesced 512B row writes
        short* Yb = (short*)Y + (size_t)b * CHW_;
#pragma unroll
        for (int h = 0; h < 2; ++h) {
#pragma unroll
            for (int mt = 0; mt < 2; ++mt)
#pragma unroll
                for (int q = 0; q < 4; ++q) {
                    int nt = h * 4 + q;
                    int nr = q * 16 + l16;            // 0..63 within half
                    int mloc = wave * 32 + mt * 16 + quad * 4;
                    __hip_bfloat16 arr[4];
#pragma unroll
                    for (int r = 0; r < 4; ++r) arr[r] = __float2bfloat16(acc[mt][nt][r]);
                    *(int2*)&smem[nr * 264 + mloc] = *(int2*)arr;
                }
            __syncthreads();
#pragma unroll
            for (int j = 0; j < 4; ++j) {
                int id = t + 512 * j;                 // 0..2047: 64 rows x 32 chunks(16B)
                int row = id >> 5, c = id & 31;
                int4 v = *(const int4*)&smem[row * 264 + c * 8];
                *(int4*)(Yb + (size_t)(n0 + h * 64 + row) * 256 + c * 8) = v;
            }
            __syncthreads();
        }
    } else {
        float* Yb = (float*)Y + (size_t)b * CHW_;
#pragma unroll
        for (int mt = 0; mt < 2; ++mt)
#pragma unroll
            for (int nt = 0; nt < 8; ++nt)
#pragma unroll
                for (int r = 0; r < 4; ++r) {
                    int m = wave * 32 + mt * 16 + quad * 4 + r;
                    int n = n0 + nt * 16 + l16;
                    Yb[(size_t)m * HW_ + n] = acc[mt][nt][r];
                }
    }
    if constexpr (STATS) {
        // wave's 32 m-rows are exactly one group: grp = b*8 + wave
        float s1 = 0.f, s2 = 0.f;
#pragma unroll
        for (int mt = 0; mt < 2; ++mt)
#pragma unroll
            for (int nt = 0; nt < 8; ++nt)
#pragma unroll
                for (int r = 0; r < 4; ++r) {
                    float v = acc[mt][nt][r];
                    s1 += v;
                    s2 += v * v;
                }
#pragma unroll
        for (int o = 32; o; o >>= 1) {
            s1 += __shfl_down(s1, o);
            s2 += __shfl_down(s2, o);
        }
        if (lane == 0) {
            int grp = b * NH_ + wave;
            atomicAdd(&stats[grp * 2 + 0], s1);
            atomicAdd(&stats[grp * 2 + 1], s2);
        }
    }
}

// ---------------- deformable bilinear sampling from V^T bf16 [b][p][c] -> sampledT bf16 [b][p][c] ----------------
// block 256 = 8 pixels x 8 heads x 4 chunks; 4 consecutive lanes = the 4x16B bf16 chunks of one
// (pixel,head) 64B tap segment -> every load reads contiguous 64B lines.
__global__ __launch_bounds__(256) void sample_kernel(const __hip_bfloat16* __restrict__ VT,
                                                     const float* __restrict__ off,
                                                     __hip_bfloat16* __restrict__ sT) {
    int t = threadIdx.x;
    int chunk = t & 3;                 // 16B (8ch) chunk within head's 64B segment
    int g = t >> 2;                    // 0..63 = pixel_sub*8 + head
    int head = g & 7;
    int p = blockIdx.x * 8 + (g >> 3);
    int b = blockIdx.z;
    int h = p >> 7, w = p & 127;
    const float* ob = off + ((size_t)b * 16 + head * 2) * HW_ + p;
    float dy = ob[0], dx = ob[HW_];    // broadcast within 4-lane group
    float gy = h * (2.0f / 127.0f) - 1.0f;
    float gx = w * (2.0f / 127.0f) - 1.0f;
    float sx = fminf(fmaxf(gx + dx, -1.0f), 1.0f);
    float sy = fminf(fmaxf(gy + dy, -1.0f), 1.0f);
    float ix = (sx + 1.0f) * 0.5f * 127.0f;
    float iy = (sy + 1.0f) * 0.5f * 127.0f;
    float x0f = floorf(ix), y0f = floorf(iy);
    float wx = ix - x0f, wy = iy - y0f;
    int x0 = min(max((int)x0f, 0), 127);
    int x1 = min((int)x0f + 1, 127);
    int y0 = min(max((int)y0f, 0), 127);
    int y1 = min((int)y0f + 1, 127);
    float w00 = (1.f - wx) * (1.f - wy), w01 = wx * (1.f - wy);
    float w10 = (1.f - wx) * wy, w11 = wx * wy;
    const short* Vb = (const short*)VT + (size_t)b * CHW_ + head * 32 + chunk * 8;
    short8 v00 = *(const short8*)(Vb + (size_t)(y0 * W_ + x0) * C_);
    short8 v01 = *(const short8*)(Vb + (size_t)(y0 * W_ + x1) * C_);
    short8 v10 = *(const short8*)(Vb + (size_t)(y1 * W_ + x0) * C_);
    short8 v11 = *(const short8*)(Vb + (size_t)(y1 * W_ + x1) * C_);
    __hip_bfloat16 arr[8];
#pragma unroll
    for (int j = 0; j < 8; ++j) {
        float f = __bfloat162float(((const __hip_bfloat16*)&v00)[j]) * w00 +
                  __bfloat162float(((const __hip_bfloat16*)&v01)[j]) * w01 +
                  __bfloat162float(((const __hip_bfloat16*)&v10)[j]) * w10 +
                  __bfloat162float(((const __hip_bfloat16*)&v11)[j]) * w11;
        arr[j] = __float2bfloat16(f);
    }
    __hip_bfloat16* op = sT + ((size_t)b * HW_ + p) * C_ + head * 32 + chunk * 8;
    *(int4*)op = *(int4*)arr;
}

// ---------------- normalize + affine + residual (float4) ----------------
__global__ __launch_bounds__(256) void final_kernel(const float* __restrict__ x,
                                                    const float* __restrict__ stats,
                                                    const float* __restrict__ gamma,
                                                    const float* __restrict__ beta,
                                                    float* __restrict__ out) {
    int idx = (blockIdx.x * 256 + threadIdx.x) * 4;
    int c = (idx >> 14) & 255;
    int b = idx >> 22;
    int grp = b * NH_ + (c >> 5);
    const float invN = 1.0f / (float)(HD_ * HW_);
    float mu = stats[grp * 2 + 0] * invN;
    float var = stats[grp * 2 + 1] * invN - mu * mu;
    float r = rsqrtf(var + 1e-5f);
    float g = gamma[c], be = beta[c];
    float4 v = *(const float4*)&out[idx];
    float4 xv = *(const float4*)&x[idx];
    float4 o;
    o.x = xv.x + (v.x - mu) * r * g + be;
    o.y = xv.y + (v.y - mu) * r * g + be;
    o.z = xv.z + (v.z - mu) * r * g + be;
    o.w = xv.w + (v.w - mu) * r * g + be;
    *(float4*)&out[idx] = o;
}

extern "C" void kernel_launch(void* const* d_in, const int* in_sizes, int n_in,
                              void* d_out, int out_size, void* d_ws, size_t ws_size,
                              hipStream_t stream) {
    const float* x     = (const float*)d_in[0];
    const float* dww   = (const float*)d_in[1];
    const float* offw  = (const float*)d_in[2];
    const float* offb  = (const float*)d_in[3];
    const float* vw    = (const float*)d_in[4];
    const float* ow    = (const float*)d_in[5];
    const float* gamma = (const float*)d_in[6];
    const float* beta  = (const float*)d_in[7];
    float* out = (float*)d_out;
    float* ws_f = (float*)d_ws;

    // ws layout (floats)
    float* partials = ws_f;                                   // 16,777,216 f
    float* off_buf  = ws_f + 16777216;                        //  2,097,152 f
    float* stats    = ws_f + 18874368;                        //        256 f
    __hip_bfloat16* wvb = (__hip_bfloat16*)(ws_f + 18874624); //  65,536 bf16
    __hip_bfloat16* wob = wvb + 65536;                        //  65,536 bf16
    __hip_bfloat16* xT  = (__hip_bfloat16*)(ws_f + 18940160); //  33,554,432 bf16
    __hip_bfloat16* sT  = (__hip_bfloat16*)partials;          //  alias region A (partials dead after offreduce)
    __hip_bfloat16* vT  = (__hip_bfloat16*)out;               //  V^T bf16 staging in d_out (64MB of 128MB)

    // 1. weight converts + x transpose to bf16
    wconv_kernel<<<256, 256, 0, stream>>>(vw, ow, wvb, wob);
    xt_kernel<<<dim3(256, 4, 8), 256, 0, stream>>>(x, xT);
    // 2. fused dwconv + partial offset proj
    fused_offset_kernel<<<dim3(16, 8, 8), 256, 0, stream>>>(x, dww, offw, partials);
    offreduce_kernel<<<8192, 256, 0, stream>>>(partials, offb, off_buf);
    // 3. V^T[b][p][c] = (vw * x)^T bf16 (full-M 8-wave dbuf DMA GEMM)
    mfma_gemm<true, false><<<dim3(128, 1, 8), 512, 0, stream>>>(wvb, xT, (void*)vT, nullptr);
    // 4. deformable sampling from V^T bf16 -> sT bf16 [p][c]
    sample_kernel<<<dim3(2048, 1, 8), 256, 0, stream>>>(vT, off_buf, sT);
    // 5. out = ow * sampled + fused group stats -> d_out fp32
    hipMemsetAsync(stats, 0, 128 * sizeof(float), stream);
    mfma_gemm<false, true><<<dim3(128, 1, 8), 512, 0, stream>>>(wob, sT, (void*)out, stats);
    // 6. normalize + residual
    final_kernel<<<NTOT / 1024, 256, 0, stream>>>(x, stats, gamma, beta, out);
}

// Round 10
// 545.920 us; speedup vs baseline: 1.6220x; 1.6220x over previous
//
#include <hip/hip_runtime.h>
#include <hip/hip_bf16.h>

#define B_ 8
#define C_ 256
#define H_ 128
#define W_ 128
#define HW_ 16384
#define CHW_ (C_ * HW_)
#define NH_ 8
#define HD_ 32
#define NTOT (B_ * CHW_)   // 33,554,432

typedef short short8 __attribute__((ext_vector_type(8)));
typedef float f32x4 __attribute__((ext_vector_type(4)));

// ---------------- weight fp32 -> bf16 convert ----------------
__global__ __launch_bounds__(256) void wconv_kernel(const float* __restrict__ vw,
                                                    const float* __restrict__ ow,
                                                    __hip_bfloat16* __restrict__ wvb,
                                                    __hip_bfloat16* __restrict__ wob) {
    int i = blockIdx.x * 256 + threadIdx.x;   // 65536
    wvb[i] = __float2bfloat16(vw[i]);
    wob[i] = __float2bfloat16(ow[i]);
}

// ---------------- x [b][c][p] fp32 -> xT [b][p][c] bf16 (LDS-tiled transpose) ----------------
__global__ __launch_bounds__(256) void xt_kernel(const float* __restrict__ x,
                                                 __hip_bfloat16* __restrict__ xT) {
    __shared__ float tile[64][68];
    int t = threadIdx.x;
    int p0 = blockIdx.x * 64, c0 = blockIdx.y * 64, b = blockIdx.z;
    const float* xb = x + ((size_t)b * C_ + c0) * HW_ + p0;
#pragma unroll
    for (int l = 0; l < 4; ++l) {
        int idx = t + 256 * l;
        int row = idx >> 4, cf = idx & 15;
        float4 v = *(const float4*)&xb[(size_t)row * HW_ + cf * 4];
        *(float4*)&tile[row][cf * 4] = v;
    }
    __syncthreads();
    __hip_bfloat16* op = xT + ((size_t)b * HW_ + p0) * C_ + c0;
#pragma unroll
    for (int l = 0; l < 2; ++l) {
        int idx = t + 256 * l;
        int p = idx & 63, oct = idx >> 6;    // oct 0..7
        __hip_bfloat16 arr[8];
#pragma unroll
        for (int j = 0; j < 8; ++j) arr[j] = __float2bfloat16(tile[oct * 8 + j][p]);
        *(int4*)(op + (size_t)p * C_ + oct * 8) = *(int4*)arr;
    }
}

// ---------------- FUSED dwconv3x3 + partial offset projection ----------------
__global__ __launch_bounds__(256) void fused_offset_kernel(const float* __restrict__ x,
                                                           const float* __restrict__ dww,
                                                           const float* __restrict__ offw,
                                                           float* __restrict__ partials) {
    __shared__ float xt[4][10][136];   // 4 ch, 10 halo rows, col+4 shift, pad
    __shared__ float wT[32][16];
    __shared__ float wd[32][9];
    int t = threadIdx.x;
    int rt = blockIdx.x, cg = blockIdx.y, b = blockIdx.z;
    int h0 = rt * 8, c0 = cg * 32;
    for (int i = t; i < 512; i += 256) { int o = i >> 5, c = i & 31; wT[c][o] = offw[o * 256 + c0 + c]; }
    for (int i = t; i < 288; i += 256) { wd[i / 9][i % 9] = dww[(c0 + i / 9) * 9 + i % 9]; }
    const float* xb = x + ((size_t)b * C_ + c0) * HW_;
    int col = t & 127;
    int sb = (t >> 7) * 4;             // row-strip base 0 or 4
    float acc[4][16] = {};
    for (int cc0 = 0; cc0 < 32; cc0 += 4) {
        __syncthreads();
#pragma unroll
        for (int l = 0; l < 5; ++l) {
            int idx = t + 256 * l;             // 0..1279
            int pr = idx >> 5, c4 = idx & 31;
            int cc = pr / 10, r = pr - cc * 10;
            int gh = h0 - 1 + r;
            float4 v = make_float4(0.f, 0.f, 0.f, 0.f);
            if (gh >= 0 && gh < H_)
                v = *(const float4*)&xb[(size_t)(cc0 + cc) * HW_ + gh * W_ + c4 * 4];
            *(float4*)&xt[cc][r][4 + c4 * 4] = v;
        }
        if (t < 80) { int pr = t >> 1, side = t & 1; xt[pr / 10][pr % 10][side ? 132 : 3] = 0.f; }
        __syncthreads();
#pragma unroll
        for (int cc = 0; cc < 4; ++cc) {
            float win[6][3];
#pragma unroll
            for (int rr = 0; rr < 6; ++rr)
#pragma unroll
                for (int kk = 0; kk < 3; ++kk)
                    win[rr][kk] = xt[cc][sb + rr][col + 3 + kk];
            float w9[9];
#pragma unroll
            for (int k9 = 0; k9 < 9; ++k9) w9[k9] = wd[cc0 + cc][k9];
#pragma unroll
            for (int j = 0; j < 4; ++j) {
                float s = 0.f;
#pragma unroll
                for (int ky = 0; ky < 3; ++ky)
#pragma unroll
                    for (int kx = 0; kx < 3; ++kx)
                        s += win[j + ky][kx] * w9[ky * 3 + kx];
#pragma unroll
                for (int o = 0; o < 16; ++o) acc[j][o] += s * wT[cc0 + cc][o];
            }
        }
    }
    float* pb = partials + (size_t)(cg * 8 + b) * 16 * HW_;
#pragma unroll
    for (int o = 0; o < 16; ++o)
#pragma unroll
        for (int j = 0; j < 4; ++j)
            pb[(size_t)o * HW_ + (h0 + sb + j) * W_ + col] = acc[j][o];
}

// ---------------- sum 8 partials + bias + fast tanh ----------------
__global__ __launch_bounds__(256) void offreduce_kernel(const float* __restrict__ partials,
                                                        const float* __restrict__ offb,
                                                        float* __restrict__ off_buf) {
    int i = blockIdx.x * 256 + threadIdx.x;     // 0..2097151 over [b][o][p]
    float s = 0.f;
#pragma unroll
    for (int cg = 0; cg < 8; ++cg) s += partials[(size_t)cg * 2097152 + i];
    int o = (i >> 14) & 15;
    float z = s + offb[o];
    // tanh(z) = 1 - 2/(exp2(2z*log2e)+1)  (exact; v_exp_f32-based, saturates at +/-1)
    float e = exp2f(z * 2.885390082f);
    off_buf[i] = (1.0f - __fdividef(2.0f, e + 1.0f)) * 0.5f;
}

// ---------------- bf16 MFMA GEMM: Y[b](256 x HW) = W(256x256) * X[b], X given as X^T [p][c] ----------------
// R9 structure with the spill bug fixed: __launch_bounds__(512) WITHOUT a min-waves clamp
// (R9's (512,6) forced VGPR=40 -> accumulator spill -> 728MB scratch writes).
// Full M=256 per block (8 waves x 32 m-rows), N-tile 128, 512 thr, BK=32, 8 steps.
// LDS 48KB -> 3 blocks/CU (24 waves) when VGPR <= ~85, else 2 blocks (16 waves) -- both > R8.
//  - global_load_lds width=16 DMA staging; next step staged BEFORE compute; one barrier/step.
//  - LDS linear for DMA; global SOURCE slot XOR-swizzled; ds_read same XOR (both-sides involution).
//  - TRANS epilogue: two 64-row halves staged via LDS (stride 264), coalesced 512B row writes.
// TRANS: write Y^T [n][c] as bf16 (for sampling).  STATS: accumulate group sum/sumsq.
template<bool TRANS, bool STATS>
__global__ __launch_bounds__(512) void mfma_gemm(const __hip_bfloat16* __restrict__ Wb,
                                                 const __hip_bfloat16* __restrict__ Xt,
                                                 void* __restrict__ Y,
                                                 float* __restrict__ stats) {
    // 24576 shorts = 48KB: A dbuf [2][8192] at 0, B dbuf [2][4096] at 16384.
    // TRANS epilogue reuse: [64 rows][264 stride] = 16896 shorts.
    __shared__ __align__(16) short smem[24576];
    int t = threadIdx.x;
    int wave = t >> 6, lane = t & 63;
    int quad = lane >> 4, l16 = lane & 15;
    int b = blockIdx.z;
    int n0 = blockIdx.x * 128;
    const short* Wp = (const short*)Wb;                                   // full 256 x 256
    const short* Xp = (const short*)Xt + ((size_t)b * HW_ + n0) * 256;

    // staging: A tile = 1024 chunks of 16B (256 rows x 4 slots), 2/thread; B tile = 512 chunks, 1/thread.
    // LDS dest lane-linear (DMA semantics); global src slot XOR-swizzled.
    int iA0 = t, iA1 = t + 512;
    int rA0 = iA0 >> 2, rA1 = iA1 >> 2;
    int sA0 = (iA0 & 3) ^ ((rA0 >> 1) & 3);
    int sA1 = (iA1 & 3) ^ ((rA1 >> 1) & 3);
    int rB0 = t >> 2;
    int sB0 = (t & 3) ^ ((rB0 >> 1) & 3);

#define STAGE(buf, ko)                                                                                          \
    do {                                                                                                        \
        short* Asm_ = smem + (buf) * 8192;                                                                      \
        short* Bsm_ = smem + 16384 + (buf) * 4096;                                                              \
        __builtin_amdgcn_global_load_lds(Wp + (size_t)rA0 * 256 + (ko) + sA0 * 8, Asm_ + iA0 * 8, 16, 0, 0);    \
        __builtin_amdgcn_global_load_lds(Wp + (size_t)rA1 * 256 + (ko) + sA1 * 8, Asm_ + iA1 * 8, 16, 0, 0);    \
        __builtin_amdgcn_global_load_lds(Xp + (size_t)rB0 * 256 + (ko) + sB0 * 8, Bsm_ + t * 8, 16, 0, 0);      \
    } while (0)

    f32x4 acc[2][8];
#pragma unroll
    for (int mt = 0; mt < 2; ++mt)
#pragma unroll
        for (int nt = 0; nt < 8; ++nt) acc[mt][nt] = (f32x4){0.f, 0.f, 0.f, 0.f};

    STAGE(0, 0);
    __syncthreads();                       // drain prologue stage

#pragma unroll
    for (int kk = 0; kk < 8; ++kk) {
        int cur = kk & 1;
        if (kk < 7) STAGE(cur ^ 1, (kk + 1) * 32);   // prefetch next tile BEFORE compute
        __builtin_amdgcn_sched_barrier(0);            // pin DMA issue above the ds_reads
        const short* Ac = smem + cur * 8192;
        const short* Bc = smem + 16384 + cur * 4096;
        short8 af[2], bf[8];
#pragma unroll
        for (int mt = 0; mt < 2; ++mt) {
            int r = wave * 32 + mt * 16 + l16;        // 0..255
            int sl = quad ^ ((r >> 1) & 3);
            af[mt] = *(const short8*)&Ac[r * 32 + sl * 8];
        }
#pragma unroll
        for (int nt = 0; nt < 8; ++nt) {
            int r = nt * 16 + l16;                    // 0..127
            int sl = quad ^ ((r >> 1) & 3);
            bf[nt] = *(const short8*)&Bc[r * 32 + sl * 8];
        }
#pragma unroll
        for (int mt = 0; mt < 2; ++mt)
#pragma unroll
            for (int nt = 0; nt < 8; ++nt)
                acc[mt][nt] = __builtin_amdgcn_mfma_f32_16x16x32_bf16(af[mt], bf[nt], acc[mt][nt], 0, 0, 0);
        __syncthreads();                   // ONE barrier/step: drains prefetch (issued pre-compute)
    }
#undef STAGE

    if constexpr (TRANS) {
        // two 64-n-row halves: stage [64][264] bf16 in LDS, then coalesced 512B row writes
        short* Yb = (short*)Y + (size_t)b * CHW_;
#pragma unroll
        for (int h = 0; h < 2; ++h) {
#pragma unroll
            for (int mt = 0; mt < 2; ++mt)
#pragma unroll
                for (int q = 0; q < 4; ++q) {
                    int nt = h * 4 + q;
                    int nr = q * 16 + l16;            // 0..63 within half
                    int mloc = wave * 32 + mt * 16 + quad * 4;
                    __hip_bfloat16 arr[4];
#pragma unroll
                    for (int r = 0; r < 4; ++r) arr[r] = __float2bfloat16(acc[mt][nt][r]);
                    *(int2*)&smem[nr * 264 + mloc] = *(int2*)arr;
                }
            __syncthreads();
#pragma unroll
            for (int j = 0; j < 4; ++j) {
                int id = t + 512 * j;                 // 0..2047: 64 rows x 32 chunks(16B)
                int row = id >> 5, c = id & 31;
                int4 v = *(const int4*)&smem[row * 264 + c * 8];
                *(int4*)(Yb + (size_t)(n0 + h * 64 + row) * 256 + c * 8) = v;
            }
            __syncthreads();
        }
    } else {
        float* Yb = (float*)Y + (size_t)b * CHW_;
#pragma unroll
        for (int mt = 0; mt < 2; ++mt)
#pragma unroll
            for (int nt = 0; nt < 8; ++nt)
#pragma unroll
                for (int r = 0; r < 4; ++r) {
                    int m = wave * 32 + mt * 16 + quad * 4 + r;
                    int n = n0 + nt * 16 + l16;
                    Yb[(size_t)m * HW_ + n] = acc[mt][nt][r];
                }
    }
    if constexpr (STATS) {
        // wave's 32 m-rows are exactly one group: grp = b*8 + wave
        float s1 = 0.f, s2 = 0.f;
#pragma unroll
        for (int mt = 0; mt < 2; ++mt)
#pragma unroll
            for (int nt = 0; nt < 8; ++nt)
#pragma unroll
                for (int r = 0; r < 4; ++r) {
                    float v = acc[mt][nt][r];
                    s1 += v;
                    s2 += v * v;
                }
#pragma unroll
        for (int o = 32; o; o >>= 1) {
            s1 += __shfl_down(s1, o);
            s2 += __shfl_down(s2, o);
        }
        if (lane == 0) {
            int grp = b * NH_ + wave;
            atomicAdd(&stats[grp * 2 + 0], s1);
            atomicAdd(&stats[grp * 2 + 1], s2);
        }
    }
}

// ---------------- deformable bilinear sampling from V^T bf16 [b][p][c] -> sampledT bf16 [b][p][c] ----------------
// block 256 = 8 pixels x 8 heads x 4 chunks; 4 consecutive lanes = the 4x16B bf16 chunks of one
// (pixel,head) 64B tap segment -> every load reads contiguous 64B lines.
__global__ __launch_bounds__(256) void sample_kernel(const __hip_bfloat16* __restrict__ VT,
                                                     const float* __restrict__ off,
                                                     __hip_bfloat16* __restrict__ sT) {
    int t = threadIdx.x;
    int chunk = t & 3;                 // 16B (8ch) chunk within head's 64B segment
    int g = t >> 2;                    // 0..63 = pixel_sub*8 + head
    int head = g & 7;
    int p = blockIdx.x * 8 + (g >> 3);
    int b = blockIdx.z;
    int h = p >> 7, w = p & 127;
    const float* ob = off + ((size_t)b * 16 + head * 2) * HW_ + p;
    float dy = ob[0], dx = ob[HW_];    // broadcast within 4-lane group
    float gy = h * (2.0f / 127.0f) - 1.0f;
    float gx = w * (2.0f / 127.0f) - 1.0f;
    float sx = fminf(fmaxf(gx + dx, -1.0f), 1.0f);
    float sy = fminf(fmaxf(gy + dy, -1.0f), 1.0f);
    float ix = (sx + 1.0f) * 0.5f * 127.0f;
    float iy = (sy + 1.0f) * 0.5f * 127.0f;
    float x0f = floorf(ix), y0f = floorf(iy);
    float wx = ix - x0f, wy = iy - y0f;
    int x0 = min(max((int)x0f, 0), 127);
    int x1 = min((int)x0f + 1, 127);
    int y0 = min(max((int)y0f, 0), 127);
    int y1 = min((int)y0f + 1, 127);
    float w00 = (1.f - wx) * (1.f - wy), w01 = wx * (1.f - wy);
    float w10 = (1.f - wx) * wy, w11 = wx * wy;
    const short* Vb = (const short*)VT + (size_t)b * CHW_ + head * 32 + chunk * 8;
    short8 v00 = *(const short8*)(Vb + (size_t)(y0 * W_ + x0) * C_);
    short8 v01 = *(const short8*)(Vb + (size_t)(y0 * W_ + x1) * C_);
    short8 v10 = *(const short8*)(Vb + (size_t)(y1 * W_ + x0) * C_);
    short8 v11 = *(const short8*)(Vb + (size_t)(y1 * W_ + x1) * C_);
    __hip_bfloat16 arr[8];
#pragma unroll
    for (int j = 0; j < 8; ++j) {
        float f = __bfloat162float(((const __hip_bfloat16*)&v00)[j]) * w00 +
                  __bfloat162float(((const __hip_bfloat16*)&v01)[j]) * w01 +
                  __bfloat162float(((const __hip_bfloat16*)&v10)[j]) * w10 +
                  __bfloat162float(((const __hip_bfloat16*)&v11)[j]) * w11;
        arr[j] = __float2bfloat16(f);
    }
    __hip_bfloat16* op = sT + ((size_t)b * HW_ + p) * C_ + head * 32 + chunk * 8;
    *(int4*)op = *(int4*)arr;
}

// ---------------- normalize + affine + residual (float4) ----------------
__global__ __launch_bounds__(256) void final_kernel(const float* __restrict__ x,
                                                    const float* __restrict__ stats,
                                                    const float* __restrict__ gamma,
                                                    const float* __restrict__ beta,
                                                    float* __restrict__ out) {
    int idx = (blockIdx.x * 256 + threadIdx.x) * 4;
    int c = (idx >> 14) & 255;
    int b = idx >> 22;
    int grp = b * NH_ + (c >> 5);
    const float invN = 1.0f / (float)(HD_ * HW_);
    float mu = stats[grp * 2 + 0] * invN;
    float var = stats[grp * 2 + 1] * invN - mu * mu;
    float r = rsqrtf(var + 1e-5f);
    float g = gamma[c], be = beta[c];
    float4 v = *(const float4*)&out[idx];
    float4 xv = *(const float4*)&x[idx];
    float4 o;
    o.x = xv.x + (v.x - mu) * r * g + be;
    o.y = xv.y + (v.y - mu) * r * g + be;
    o.z = xv.z + (v.z - mu) * r * g + be;
    o.w = xv.w + (v.w - mu) * r * g + be;
    *(float4*)&out[idx] = o;
}

extern "C" void kernel_launch(void* const* d_in, const int* in_sizes, int n_in,
                              void* d_out, int out_size, void* d_ws, size_t ws_size,
                              hipStream_t stream) {
    const float* x     = (const float*)d_in[0];
    const float* dww   = (const float*)d_in[1];
    const float* offw  = (const float*)d_in[2];
    const float* offb  = (const float*)d_in[3];
    const float* vw    = (const float*)d_in[4];
    const float* ow    = (const float*)d_in[5];
    const float* gamma = (const float*)d_in[6];
    const float* beta  = (const float*)d_in[7];
    float* out = (float*)d_out;
    float* ws_f = (float*)d_ws;

    // ws layout (floats)
    float* partials = ws_f;                                   // 16,777,216 f
    float* off_buf  = ws_f + 16777216;                        //  2,097,152 f
    float* stats    = ws_f + 18874368;                        //        256 f
    __hip_bfloat16* wvb = (__hip_bfloat16*)(ws_f + 18874624); //  65,536 bf16
    __hip_bfloat16* wob = wvb + 65536;                        //  65,536 bf16
    __hip_bfloat16* xT  = (__hip_bfloat16*)(ws_f + 18940160); //  33,554,432 bf16
    __hip_bfloat16* sT  = (__hip_bfloat16*)partials;          //  alias region A (partials dead after offreduce)
    __hip_bfloat16* vT  = (__hip_bfloat16*)out;               //  V^T bf16 staging in d_out (64MB of 128MB)

    // 1. weight converts + x transpose to bf16
    wconv_kernel<<<256, 256, 0, stream>>>(vw, ow, wvb, wob);
    xt_kernel<<<dim3(256, 4, 8), 256, 0, stream>>>(x, xT);
    // 2. fused dwconv + partial offset proj
    fused_offset_kernel<<<dim3(16, 8, 8), 256, 0, stream>>>(x, dww, offw, partials);
    offreduce_kernel<<<8192, 256, 0, stream>>>(partials, offb, off_buf);
    // 3. V^T[b][p][c] = (vw * x)^T bf16 (full-M 8-wave dbuf DMA GEMM)
    mfma_gemm<true, false><<<dim3(128, 1, 8), 512, 0, stream>>>(wvb, xT, (void*)vT, nullptr);
    // 4. deformable sampling from V^T bf16 -> sT bf16 [p][c]
    sample_kernel<<<dim3(2048, 1, 8), 256, 0, stream>>>(vT, off_buf, sT);
    // 5. out = ow * sampled + fused group stats -> d_out fp32
    hipMemsetAsync(stats, 0, 128 * sizeof(float), stream);
    mfma_gemm<false, true><<<dim3(128, 1, 8), 512, 0, stream>>>(wob, sT, (void*)out, stats);
    // 6. normalize + residual
    final_kernel<<<NTOT / 1024, 256, 0, stream>>>(x, stats, gamma, beta, out);
}

// Round 11
// 539.730 us; speedup vs baseline: 1.6406x; 1.0115x over previous
//
#include <hip/hip_runtime.h>
#include <hip/hip_bf16.h>

#define B_ 8
#define C_ 256
#define H_ 128
#define W_ 128
#define HW_ 16384
#define CHW_ (C_ * HW_)
#define NH_ 8
#define HD_ 32
#define NTOT (B_ * CHW_)   // 33,554,432

typedef short short8 __attribute__((ext_vector_type(8)));
typedef float f32x4 __attribute__((ext_vector_type(4)));

// ---------------- weight fp32 -> bf16 convert ----------------
__global__ __launch_bounds__(256) void wconv_kernel(const float* __restrict__ vw,
                                                    const float* __restrict__ ow,
                                                    __hip_bfloat16* __restrict__ wvb,
                                                    __hip_bfloat16* __restrict__ wob) {
    int i = blockIdx.x * 256 + threadIdx.x;   // 65536
    wvb[i] = __float2bfloat16(vw[i]);
    wob[i] = __float2bfloat16(ow[i]);
}

// ---------------- x [b][c][p] fp32 -> xT [b][p][c] bf16 (LDS-tiled transpose) ----------------
__global__ __launch_bounds__(256) void xt_kernel(const float* __restrict__ x,
                                                 __hip_bfloat16* __restrict__ xT) {
    __shared__ float tile[64][68];
    int t = threadIdx.x;
    int p0 = blockIdx.x * 64, c0 = blockIdx.y * 64, b = blockIdx.z;
    const float* xb = x + ((size_t)b * C_ + c0) * HW_ + p0;
#pragma unroll
    for (int l = 0; l < 4; ++l) {
        int idx = t + 256 * l;
        int row = idx >> 4, cf = idx & 15;
        float4 v = *(const float4*)&xb[(size_t)row * HW_ + cf * 4];
        *(float4*)&tile[row][cf * 4] = v;
    }
    __syncthreads();
    __hip_bfloat16* op = xT + ((size_t)b * HW_ + p0) * C_ + c0;
#pragma unroll
    for (int l = 0; l < 2; ++l) {
        int idx = t + 256 * l;
        int p = idx & 63, oct = idx >> 6;    // oct 0..7
        __hip_bfloat16 arr[8];
#pragma unroll
        for (int j = 0; j < 8; ++j) arr[j] = __float2bfloat16(tile[oct * 8 + j][p]);
        *(int4*)(op + (size_t)p * C_ + oct * 8) = *(int4*)arr;
    }
}

// ---------------- FUSED dwconv3x3 + partial offset projection ----------------
__global__ __launch_bounds__(256) void fused_offset_kernel(const float* __restrict__ x,
                                                           const float* __restrict__ dww,
                                                           const float* __restrict__ offw,
                                                           float* __restrict__ partials) {
    __shared__ float xt[4][10][136];   // 4 ch, 10 halo rows, col+4 shift, pad
    __shared__ float wT[32][16];
    __shared__ float wd[32][9];
    int t = threadIdx.x;
    int rt = blockIdx.x, cg = blockIdx.y, b = blockIdx.z;
    int h0 = rt * 8, c0 = cg * 32;
    for (int i = t; i < 512; i += 256) { int o = i >> 5, c = i & 31; wT[c][o] = offw[o * 256 + c0 + c]; }
    for (int i = t; i < 288; i += 256) { wd[i / 9][i % 9] = dww[(c0 + i / 9) * 9 + i % 9]; }
    const float* xb = x + ((size_t)b * C_ + c0) * HW_;
    int col = t & 127;
    int sb = (t >> 7) * 4;             // row-strip base 0 or 4
    float acc[4][16] = {};
    for (int cc0 = 0; cc0 < 32; cc0 += 4) {
        __syncthreads();
#pragma unroll
        for (int l = 0; l < 5; ++l) {
            int idx = t + 256 * l;             // 0..1279
            int pr = idx >> 5, c4 = idx & 31;
            int cc = pr / 10, r = pr - cc * 10;
            int gh = h0 - 1 + r;
            float4 v = make_float4(0.f, 0.f, 0.f, 0.f);
            if (gh >= 0 && gh < H_)
                v = *(const float4*)&xb[(size_t)(cc0 + cc) * HW_ + gh * W_ + c4 * 4];
            *(float4*)&xt[cc][r][4 + c4 * 4] = v;
        }
        if (t < 80) { int pr = t >> 1, side = t & 1; xt[pr / 10][pr % 10][side ? 132 : 3] = 0.f; }
        __syncthreads();
#pragma unroll
        for (int cc = 0; cc < 4; ++cc) {
            float win[6][3];
#pragma unroll
            for (int rr = 0; rr < 6; ++rr)
#pragma unroll
                for (int kk = 0; kk < 3; ++kk)
                    win[rr][kk] = xt[cc][sb + rr][col + 3 + kk];
            float w9[9];
#pragma unroll
            for (int k9 = 0; k9 < 9; ++k9) w9[k9] = wd[cc0 + cc][k9];
#pragma unroll
            for (int j = 0; j < 4; ++j) {
                float s = 0.f;
#pragma unroll
                for (int ky = 0; ky < 3; ++ky)
#pragma unroll
                    for (int kx = 0; kx < 3; ++kx)
                        s += win[j + ky][kx] * w9[ky * 3 + kx];
#pragma unroll
                for (int o = 0; o < 16; ++o) acc[j][o] += s * wT[cc0 + cc][o];
            }
        }
    }
    float* pb = partials + (size_t)(cg * 8 + b) * 16 * HW_;
#pragma unroll
    for (int o = 0; o < 16; ++o)
#pragma unroll
        for (int j = 0; j < 4; ++j)
            pb[(size_t)o * HW_ + (h0 + sb + j) * W_ + col] = acc[j][o];
}

// ---------------- sum 8 partials + bias + fast tanh ----------------
__global__ __launch_bounds__(256) void offreduce_kernel(const float* __restrict__ partials,
                                                        const float* __restrict__ offb,
                                                        float* __restrict__ off_buf) {
    int i = blockIdx.x * 256 + threadIdx.x;     // 0..2097151 over [b][o][p]
    float s = 0.f;
#pragma unroll
    for (int cg = 0; cg < 8; ++cg) s += partials[(size_t)cg * 2097152 + i];
    int o = (i >> 14) & 15;
    float z = s + offb[o];
    // tanh(z) = 1 - 2/(exp2(2z*log2e)+1)  (exact; v_exp_f32-based, saturates at +/-1)
    float e = exp2f(z * 2.885390082f);
    off_buf[i] = (1.0f - __fdividef(2.0f, e + 1.0f)) * 0.5f;
}

// ---------------- bf16 MFMA GEMM: Y[b](256 x HW) = W(256x256) * X[b], X given as X^T [p][c] ----------------
// T3+T4 counted-vmcnt pipeline (m201 recipe) on the R10 skeleton:
//  - 3 LDS buffers (72KB), prefetch distance 2; per step: {vmcnt(3) lgkmcnt(0); s_barrier;
//    STAGE(kk+2); compute kk}. vmcnt NEVER drains to 0 in the main loop -- the next tile's
//    3 DMA loads stay in flight across the barrier (the drain-per-step was the ~5000cy/step stall).
//  - lgkmcnt(0) before the barrier retires all step-(kk-1) ds_reads, so the DMA issued after the
//    barrier into buffer (kk+2)%3 (== tile kk-1's buffer) cannot race those reads.
//  - Full M=256 per block (8 waves), N-tile 128, 512 thr, BK=32, 8 steps. VGPR ~68, no clamp.
//  - global SOURCE slot XOR-swizzled; ds_read same XOR (both-sides involution); LDS linear for DMA.
//  - TRANS epilogue: two 64-row halves staged via LDS (stride 264), coalesced 512B row writes.
// TRANS: write Y^T [n][c] as bf16 (for sampling).  STATS: accumulate group sum/sumsq.
template<bool TRANS, bool STATS>
__global__ __launch_bounds__(512) void mfma_gemm(const __hip_bfloat16* __restrict__ Wb,
                                                 const __hip_bfloat16* __restrict__ Xt,
                                                 void* __restrict__ Y,
                                                 float* __restrict__ stats) {
    // 36864 shorts = 72KB: buffer i at i*12288 (A 8192 + B 4096).
    // TRANS epilogue reuse: [64 rows][264 stride] = 16896 shorts.
    __shared__ __align__(16) short smem[36864];
    int t = threadIdx.x;
    int wave = t >> 6, lane = t & 63;
    int quad = lane >> 4, l16 = lane & 15;
    int b = blockIdx.z;
    int n0 = blockIdx.x * 128;
    const short* Wp = (const short*)Wb;                                   // full 256 x 256
    const short* Xp = (const short*)Xt + ((size_t)b * HW_ + n0) * 256;

    // staging: A tile = 1024 chunks of 16B (256 rows x 4 slots), 2/thread; B tile = 512 chunks, 1/thread.
    // LDS dest lane-linear (DMA semantics); global src slot XOR-swizzled.
    int iA0 = t, iA1 = t + 512;
    int rA0 = iA0 >> 2, rA1 = iA1 >> 2;
    int sA0 = (iA0 & 3) ^ ((rA0 >> 1) & 3);
    int sA1 = (iA1 & 3) ^ ((rA1 >> 1) & 3);
    int rB0 = t >> 2;
    int sB0 = (t & 3) ^ ((rB0 >> 1) & 3);

#define STAGE(buf, ko)                                                                                          \
    do {                                                                                                        \
        short* Asm_ = smem + (buf) * 12288;                                                                     \
        short* Bsm_ = smem + (buf) * 12288 + 8192;                                                              \
        __builtin_amdgcn_global_load_lds(Wp + (size_t)rA0 * 256 + (ko) + sA0 * 8, Asm_ + iA0 * 8, 16, 0, 0);    \
        __builtin_amdgcn_global_load_lds(Wp + (size_t)rA1 * 256 + (ko) + sA1 * 8, Asm_ + iA1 * 8, 16, 0, 0);    \
        __builtin_amdgcn_global_load_lds(Xp + (size_t)rB0 * 256 + (ko) + sB0 * 8, Bsm_ + t * 8, 16, 0, 0);      \
    } while (0)

    f32x4 acc[2][8];
#pragma unroll
    for (int mt = 0; mt < 2; ++mt)
#pragma unroll
        for (int nt = 0; nt < 8; ++nt) acc[mt][nt] = (f32x4){0.f, 0.f, 0.f, 0.f};

    // prologue: stage tiles 0 and 1 (distance 2)
    STAGE(0, 0);
    STAGE(1, 32);

#pragma unroll
    for (int kk = 0; kk < 8; ++kk) {
        // wait for OWN tile-kk loads only; tile kk+1's 3 loads stay in flight (counted vmcnt).
        // lgkmcnt(0) retires step-(kk-1) ds_reads before the barrier (overwrite-race fence).
        if (kk < 7) asm volatile("s_waitcnt vmcnt(3) lgkmcnt(0)" ::: "memory");
        else        asm volatile("s_waitcnt vmcnt(0) lgkmcnt(0)" ::: "memory");
        __builtin_amdgcn_sched_barrier(0);
        __builtin_amdgcn_s_barrier();
        __builtin_amdgcn_sched_barrier(0);
        if (kk < 6) STAGE((kk + 2) % 3, (kk + 2) * 32);   // prefetch tile kk+2 into freed buffer
        __builtin_amdgcn_sched_barrier(0);
        const short* Ac = smem + (kk % 3) * 12288;
        const short* Bc = smem + (kk % 3) * 12288 + 8192;
        short8 af[2], bf[8];
#pragma unroll
        for (int mt = 0; mt < 2; ++mt) {
            int r = wave * 32 + mt * 16 + l16;        // 0..255
            int sl = quad ^ ((r >> 1) & 3);
            af[mt] = *(const short8*)&Ac[r * 32 + sl * 8];
        }
#pragma unroll
        for (int nt = 0; nt < 8; ++nt) {
            int r = nt * 16 + l16;                    // 0..127
            int sl = quad ^ ((r >> 1) & 3);
            bf[nt] = *(const short8*)&Bc[r * 32 + sl * 8];
        }
#pragma unroll
        for (int mt = 0; mt < 2; ++mt)
#pragma unroll
            for (int nt = 0; nt < 8; ++nt)
                acc[mt][nt] = __builtin_amdgcn_mfma_f32_16x16x32_bf16(af[mt], bf[nt], acc[mt][nt], 0, 0, 0);
    }
#undef STAGE
    __syncthreads();    // full drain before smem reuse in epilogue

    if constexpr (TRANS) {
        // two 64-n-row halves: stage [64][264] bf16 in LDS, then coalesced 512B row writes
        short* Yb = (short*)Y + (size_t)b * CHW_;
#pragma unroll
        for (int h = 0; h < 2; ++h) {
#pragma unroll
            for (int mt = 0; mt < 2; ++mt)
#pragma unroll
                for (int q = 0; q < 4; ++q) {
                    int nt = h * 4 + q;
                    int nr = q * 16 + l16;            // 0..63 within half
                    int mloc = wave * 32 + mt * 16 + quad * 4;
                    __hip_bfloat16 arr[4];
#pragma unroll
                    for (int r = 0; r < 4; ++r) arr[r] = __float2bfloat16(acc[mt][nt][r]);
                    *(int2*)&smem[nr * 264 + mloc] = *(int2*)arr;
                }
            __syncthreads();
#pragma unroll
            for (int j = 0; j < 4; ++j) {
                int id = t + 512 * j;                 // 0..2047: 64 rows x 32 chunks(16B)
                int row = id >> 5, c = id & 31;
                int4 v = *(const int4*)&smem[row * 264 + c * 8];
                *(int4*)(Yb + (size_t)(n0 + h * 64 + row) * 256 + c * 8) = v;
            }
            __syncthreads();
        }
    } else {
        float* Yb = (float*)Y + (size_t)b * CHW_;
#pragma unroll
        for (int mt = 0; mt < 2; ++mt)
#pragma unroll
            for (int nt = 0; nt < 8; ++nt)
#pragma unroll
                for (int r = 0; r < 4; ++r) {
                    int m = wave * 32 + mt * 16 + quad * 4 + r;
                    int n = n0 + nt * 16 + l16;
                    Yb[(size_t)m * HW_ + n] = acc[mt][nt][r];
                }
    }
    if constexpr (STATS) {
        // wave's 32 m-rows are exactly one group: grp = b*8 + wave
        float s1 = 0.f, s2 = 0.f;
#pragma unroll
        for (int mt = 0; mt < 2; ++mt)
#pragma unroll
            for (int nt = 0; nt < 8; ++nt)
#pragma unroll
                for (int r = 0; r < 4; ++r) {
                    float v = acc[mt][nt][r];
                    s1 += v;
                    s2 += v * v;
                }
#pragma unroll
        for (int o = 32; o; o >>= 1) {
            s1 += __shfl_down(s1, o);
            s2 += __shfl_down(s2, o);
        }
        if (lane == 0) {
            int grp = b * NH_ + wave;
            atomicAdd(&stats[grp * 2 + 0], s1);
            atomicAdd(&stats[grp * 2 + 1], s2);
        }
    }
}

// ---------------- deformable bilinear sampling from V^T bf16 [b][p][c] -> sampledT bf16 [b][p][c] ----------------
// block 256 = 8 pixels x 8 heads x 4 chunks; 4 consecutive lanes = the 4x16B bf16 chunks of one
// (pixel,head) 64B tap segment -> every load reads contiguous 64B lines.
__global__ __launch_bounds__(256) void sample_kernel(const __hip_bfloat16* __restrict__ VT,
                                                     const float* __restrict__ off,
                                                     __hip_bfloat16* __restrict__ sT) {
    int t = threadIdx.x;
    int chunk = t & 3;                 // 16B (8ch) chunk within head's 64B segment
    int g = t >> 2;                    // 0..63 = pixel_sub*8 + head
    int head = g & 7;
    int p = blockIdx.x * 8 + (g >> 3);
    int b = blockIdx.z;
    int h = p >> 7, w = p & 127;
    const float* ob = off + ((size_t)b * 16 + head * 2) * HW_ + p;
    float dy = ob[0], dx = ob[HW_];    // broadcast within 4-lane group
    float gy = h * (2.0f / 127.0f) - 1.0f;
    float gx = w * (2.0f / 127.0f) - 1.0f;
    float sx = fminf(fmaxf(gx + dx, -1.0f), 1.0f);
    float sy = fminf(fmaxf(gy + dy, -1.0f), 1.0f);
    float ix = (sx + 1.0f) * 0.5f * 127.0f;
    float iy = (sy + 1.0f) * 0.5f * 127.0f;
    float x0f = floorf(ix), y0f = floorf(iy);
    float wx = ix - x0f, wy = iy - y0f;
    int x0 = min(max((int)x0f, 0), 127);
    int x1 = min((int)x0f + 1, 127);
    int y0 = min(max((int)y0f, 0), 127);
    int y1 = min((int)y0f + 1, 127);
    float w00 = (1.f - wx) * (1.f - wy), w01 = wx * (1.f - wy);
    float w10 = (1.f - wx) * wy, w11 = wx * wy;
    const short* Vb = (const short*)VT + (size_t)b * CHW_ + head * 32 + chunk * 8;
    short8 v00 = *(const short8*)(Vb + (size_t)(y0 * W_ + x0) * C_);
    short8 v01 = *(const short8*)(Vb + (size_t)(y0 * W_ + x1) * C_);
    short8 v10 = *(const short8*)(Vb + (size_t)(y1 * W_ + x0) * C_);
    short8 v11 = *(const short8*)(Vb + (size_t)(y1 * W_ + x1) * C_);
    __hip_bfloat16 arr[8];
#pragma unroll
    for (int j = 0; j < 8; ++j) {
        float f = __bfloat162float(((const __hip_bfloat16*)&v00)[j]) * w00 +
                  __bfloat162float(((const __hip_bfloat16*)&v01)[j]) * w01 +
                  __bfloat162float(((const __hip_bfloat16*)&v10)[j]) * w10 +
                  __bfloat162float(((const __hip_bfloat16*)&v11)[j]) * w11;
        arr[j] = __float2bfloat16(f);
    }
    __hip_bfloat16* op = sT + ((size_t)b * HW_ + p) * C_ + head * 32 + chunk * 8;
    *(int4*)op = *(int4*)arr;
}

// ---------------- normalize + affine + residual (float4) ----------------
__global__ __launch_bounds__(256) void final_kernel(const float* __restrict__ x,
                                                    const float* __restrict__ stats,
                                                    const float* __restrict__ gamma,
                                                    const float* __restrict__ beta,
                                                    float* __restrict__ out) {
    int idx = (blockIdx.x * 256 + threadIdx.x) * 4;
    int c = (idx >> 14) & 255;
    int b = idx >> 22;
    int grp = b * NH_ + (c >> 5);
    const float invN = 1.0f / (float)(HD_ * HW_);
    float mu = stats[grp * 2 + 0] * invN;
    float var = stats[grp * 2 + 1] * invN - mu * mu;
    float r = rsqrtf(var + 1e-5f);
    float g = gamma[c], be = beta[c];
    float4 v = *(const float4*)&out[idx];
    float4 xv = *(const float4*)&x[idx];
    float4 o;
    o.x = xv.x + (v.x - mu) * r * g + be;
    o.y = xv.y + (v.y - mu) * r * g + be;
    o.z = xv.z + (v.z - mu) * r * g + be;
    o.w = xv.w + (v.w - mu) * r * g + be;
    *(float4*)&out[idx] = o;
}

extern "C" void kernel_launch(void* const* d_in, const int* in_sizes, int n_in,
                              void* d_out, int out_size, void* d_ws, size_t ws_size,
                              hipStream_t stream) {
    const float* x     = (const float*)d_in[0];
    const float* dww   = (const float*)d_in[1];
    const float* offw  = (const float*)d_in[2];
    const float* offb  = (const float*)d_in[3];
    const float* vw    = (const float*)d_in[4];
    const float* ow    = (const float*)d_in[5];
    const float* gamma = (const float*)d_in[6];
    const float* beta  = (const float*)d_in[7];
    float* out = (float*)d_out;
    float* ws_f = (float*)d_ws;

    // ws layout (floats)
    float* partials = ws_f;                                   // 16,777,216 f
    float* off_buf  = ws_f + 16777216;                        //  2,097,152 f
    float* stats    = ws_f + 18874368;                        //        256 f
    __hip_bfloat16* wvb = (__hip_bfloat16*)(ws_f + 18874624); //  65,536 bf16
    __hip_bfloat16* wob = wvb + 65536;                        //  65,536 bf16
    __hip_bfloat16* xT  = (__hip_bfloat16*)(ws_f + 18940160); //  33,554,432 bf16
    __hip_bfloat16* sT  = (__hip_bfloat16*)partials;          //  alias region A (partials dead after offreduce)
    __hip_bfloat16* vT  = (__hip_bfloat16*)out;               //  V^T bf16 staging in d_out (64MB of 128MB)

    // 1. weight converts + x transpose to bf16
    wconv_kernel<<<256, 256, 0, stream>>>(vw, ow, wvb, wob);
    xt_kernel<<<dim3(256, 4, 8), 256, 0, stream>>>(x, xT);
    // 2. fused dwconv + partial offset proj
    fused_offset_kernel<<<dim3(16, 8, 8), 256, 0, stream>>>(x, dww, offw, partials);
    offreduce_kernel<<<8192, 256, 0, stream>>>(partials, offb, off_buf);
    // 3. V^T[b][p][c] = (vw * x)^T bf16 (counted-vmcnt pipelined DMA GEMM)
    mfma_gemm<true, false><<<dim3(128, 1, 8), 512, 0, stream>>>(wvb, xT, (void*)vT, nullptr);
    // 4. deformable sampling from V^T bf16 -> sT bf16 [p][c]
    sample_kernel<<<dim3(2048, 1, 8), 256, 0, stream>>>(vT, off_buf, sT);
    // 5. out = ow * sampled + fused group stats -> d_out fp32
    hipMemsetAsync(stats, 0, 128 * sizeof(float), stream);
    mfma_gemm<false, true><<<dim3(128, 1, 8), 512, 0, stream>>>(wob, sT, (void*)out, stats);
    // 6. normalize + residual
    final_kernel<<<NTOT / 1024, 256, 0, stream>>>(x, stats, gamma, beta, out);
}